// Round 8
// baseline (1112.092 us; speedup 1.0000x reference)
//
#include <hip/hip_runtime.h>

// Problem constants (from reference): N=50000, F_IN=512, F_OUT=64, C=4, E=1.6M
#define F_IN 512
#define F_OUT 64
#define NB_SHIFT 7          // bucket = tgt >> 7  (128 nodes per bucket)
#define NB_MAX 512          // >= nb = 391
#define CAP_B 5120          // records/bucket; mean 4096, sigma 64 -> +16 sigma
#define P_CHUNK 8192        // edges per partition block (two-pass over L2)

typedef float v4f __attribute__((ext_vector_type(4)));
typedef unsigned int uint32;
typedef unsigned long long u64;

// ---------------------------------------------------------------------------
// ROUND 8 = MEASUREMENT ROUND. Identical to R7 except out_kernel runs TWICE
// (bit-exact idempotent). dur_delta vs R7's 940.5 == cost(out_kernel), the
// one absolute anchor the cross-round delta system cannot provide (rocprof
// top-5 is monopolized by the harness's ~520us poison fills). Decision rule:
//   dur 1080-1130 -> out near write floor -> attack P+Q next.
//   dur 1180-1300 -> out ~2x floor       -> attack store path next.
// ---------------------------------------------------------------------------

// ---------------------------------------------------------------------------
// Phase 1: s[n][c] = tanh(dot(x[n], core_w[c]) + core_b[c]), one wave/node.
// Block 0 also zeroes the bucket reservation cursors.
// ---------------------------------------------------------------------------
__global__ __launch_bounds__(256) void signal_kernel(
    const float* __restrict__ x, const float* __restrict__ core_w,
    const float* __restrict__ core_b, float* __restrict__ s,
    uint32* __restrict__ gcur, int N, int nb) {
  if (blockIdx.x == 0) {
    for (int b = threadIdx.x; b < nb; b += 256) gcur[b] = 0;
  }

  int wave = (int)((blockIdx.x * blockDim.x + threadIdx.x) >> 6);
  int lane = threadIdx.x & 63;
  if (wave >= N) return;

  const v4f* xv = (const v4f*)(x + (size_t)wave * F_IN);
  v4f a0 = xv[lane * 2];
  v4f a1 = xv[lane * 2 + 1];

  float p[4];
#pragma unroll
  for (int c = 0; c < 4; ++c) {
    const v4f* wv = (const v4f*)(core_w + c * F_IN);
    v4f w0 = wv[lane * 2];
    v4f w1 = wv[lane * 2 + 1];
    p[c] = a0.x * w0.x + a0.y * w0.y + a0.z * w0.z + a0.w * w0.w +
           a1.x * w1.x + a1.y * w1.y + a1.z * w1.z + a1.w * w1.w;
  }
#pragma unroll
  for (int off = 32; off > 0; off >>= 1) {
#pragma unroll
    for (int c = 0; c < 4; ++c) p[c] += __shfl_down(p[c], off, 64);
  }
  if (lane == 0) {
    v4f r;
    r.x = tanhf(p[0] + core_b[0]);
    r.y = tanhf(p[1] + core_b[1]);
    r.z = tanhf(p[2] + core_b[2]);
    r.w = tanhf(p[3] + core_b[3]);
    ((v4f*)s)[wave] = r;
  }
}

// ---------------------------------------------------------------------------
// Phase P: partition P_CHUNK edges/block into bucket record arrays.
// Two passes over the (L2-resident) chunk: (A) LDS histogram, (reserve) one
// fabric atomic per non-empty bucket, (B) scatter with LDS cursor.
// Record u32 = (tgt & 127) | (src << 7)   [src < 50000 < 2^16 -> 23 bits].
// ---------------------------------------------------------------------------
__global__ __launch_bounds__(256) void part_kernel(
    const int* __restrict__ src, const int* __restrict__ tgt,
    uint32* __restrict__ gcur, uint32* __restrict__ grec, int E, int nb) {
  __shared__ uint32 hist[NB_MAX];
  __shared__ uint32 cur[NB_MAX];
  int tid = threadIdx.x;
  int start = (int)blockIdx.x * P_CHUNK;
  int end = start + P_CHUNK;
  if (end > E) end = E;

  for (int b = tid; b < nb; b += 256) hist[b] = 0;
  __syncthreads();

  // pass A: histogram (1 LDS atomic / edge)
  for (int i = start + tid; i < end; i += 256)
    atomicAdd(&hist[(uint32)tgt[i] >> NB_SHIFT], 1u);
  __syncthreads();

  // reserve: 1 returning fabric atomic per non-empty bucket
  for (int b = tid; b < nb; b += 256) {
    uint32 t = hist[b];
    cur[b] = t ? atomicAdd(&gcur[b], t) : 0u;
  }
  __syncthreads();

  // pass B: scatter (edge re-read hits this XCD's L2)
  for (int i = start + tid; i < end; i += 256) {
    uint32 v = (uint32)tgt[i];
    uint32 u = (uint32)src[i];
    uint32 b = v >> NB_SHIFT;
    uint32 pos = atomicAdd(&cur[b], 1u);       // LDS returning: cheap
    if (pos < CAP_B) grec[(size_t)b * CAP_B + pos] = (v & 127u) | (u << 7);
  }
}

// ---------------------------------------------------------------------------
// Phase Q: one block per bucket (391 blocks). Two u64 LDS accumulators per
// node (exact packed integer adds). Decode straight to avg[n] (4xf32).
// ---------------------------------------------------------------------------
__global__ __launch_bounds__(256) void agg_kernel(
    const float* __restrict__ s, const uint32* __restrict__ gcur,
    const uint32* __restrict__ grec, float* __restrict__ avg, int N) {
  int b = blockIdx.x;
  int tid = threadIdx.x;
  __shared__ u64 accA[128];
  __shared__ u64 accB[128];

  if (tid < 128) { accA[tid] = 0ull; accB[tid] = 0ull; }
  __syncthreads();

  uint32 cnt = gcur[b];
  if (cnt > CAP_B) cnt = CAP_B;
  const uint32* rp = grec + (size_t)b * CAP_B;
  for (uint32 r = tid; r < cnt; r += 256) {
    uint32 rec = rp[r];                 // coalesced
    uint32 node = rec & 127u;
    uint32 u = rec >> 7;
    v4f sv = ((const v4f*)s)[u];        // L2-resident gather (800 KB table)
    uint32 q0 = (uint32)__float2int_rn((sv.x + 1.0f) * 8388608.0f);  // 2^23
    uint32 q1 = (uint32)__float2int_rn((sv.y + 1.0f) * 8388608.0f);
    uint32 q2 = (uint32)__float2int_rn((sv.z + 1.0f) * 8388608.0f);
    uint32 q3 = (uint32)__float2int_rn((sv.w + 1.0f) * 131072.0f);   // 2^17
    atomicAdd(&accA[node], (u64)q0 | ((u64)q1 << 32));
    atomicAdd(&accB[node], (u64)q2 | ((u64)(q3 | (1u << 25)) << 32));
  }
  __syncthreads();

  int n = (b << NB_SHIFT) | tid;
  if (tid < 128 && n < N) {
    u64 wa = accA[tid];
    u64 wb = accB[tid];
    uint32 deg = (uint32)(wb >> 57);
    uint32 f3  = (uint32)(wb >> 32) & 0x1ffffffu;
    float fdeg = (float)deg;
    float inv = deg ? 1.0f / fdeg : 0.0f;
    v4f a;
    a.x = ((float)(uint32)wa         * 0x1p-23f - fdeg) * inv;
    a.y = ((float)(uint32)(wa >> 32) * 0x1p-23f - fdeg) * inv;
    a.z = ((float)(uint32)wb         * 0x1p-23f - fdeg) * inv;
    a.w = ((float)f3                 * 0x1p-17f - fdeg) * inv;
    ((v4f*)avg)[n] = a;                 // coalesced 16B
  }
}

// ---------------------------------------------------------------------------
// Phase 3: wave-per-node, grid-stride. avg[n] is plain 4xf32; 16 KB coalesced
// float4 stores per node.
// ---------------------------------------------------------------------------
__global__ __launch_bounds__(256) void out_kernel(
    const float* __restrict__ x, const float* __restrict__ avg,
    const float* __restrict__ W_out, const float* __restrict__ b_out,
    float* __restrict__ out, int N) {
  int lane = threadIdx.x & 63;
  int gwave = (int)((blockIdx.x * blockDim.x + threadIdx.x) >> 6);
  int nwaves = (int)((gridDim.x * blockDim.x) >> 6);
  int col = lane & 15;          // this lane's output quad: o = col*4 .. col*4+3

  v4f w0 = ((const v4f*)W_out)[col * 4 + 0];
  v4f w1 = ((const v4f*)W_out)[col * 4 + 1];
  v4f w2 = ((const v4f*)W_out)[col * 4 + 2];
  v4f w3 = ((const v4f*)W_out)[col * 4 + 3];
  v4f bq = ((const v4f*)b_out)[col];

  for (int n = gwave; n < N; n += nwaves) {
    v4f a = ((const v4f*)avg)[n];       // uniform addr: broadcast load

    float t0 = a.x * w0.x + a.y * w0.y + a.z * w0.z + a.w * w0.w;
    float t1 = a.x * w1.x + a.y * w1.y + a.z * w1.z + a.w * w1.w;
    float t2 = a.x * w2.x + a.y * w2.y + a.z * w2.z + a.w * w2.w;
    float t3 = a.x * w3.x + a.y * w3.y + a.z * w3.z + a.w * w3.w;

    float xval = x[(size_t)n * F_IN + lane];  // lanes hold x[n][0..63]

    v4f* ov = (v4f*)(out + (size_t)n * (F_OUT * F_OUT));
#pragma unroll
    for (int it = 0; it < 16; ++it) {
      // slot = lane + it*64 ; f = slot>>4 = (lane>>4)+it*4 ; o4 = (lane&15)*4
      float xf = __shfl(xval, (lane >> 4) + it * 4, 64);
      v4f r;
      r.x = fmaxf(xf * t0 + bq.x, 0.0f);
      r.y = fmaxf(xf * t1 + bq.y, 0.0f);
      r.z = fmaxf(xf * t2 + bq.z, 0.0f);
      r.w = fmaxf(xf * t3 + bq.w, 0.0f);
      ov[lane + it * 64] = r;
    }
  }
}

extern "C" void kernel_launch(void* const* d_in, const int* in_sizes, int n_in,
                              void* d_out, int out_size, void* d_ws, size_t ws_size,
                              hipStream_t stream) {
  const float* x      = (const float*)d_in[0];
  const int*   eidx   = (const int*)d_in[1];
  const float* core_w = (const float*)d_in[2];
  const float* core_b = (const float*)d_in[3];
  const float* W_out  = (const float*)d_in[4];
  const float* b_out  = (const float*)d_in[5];
  float* out = (float*)d_out;

  const int N = in_sizes[0] / F_IN;         // 50000
  const int E = in_sizes[1] / 2;            // 1600000
  const int* src = eidx;
  const int* tgt = eidx + E;
  const int nb = (N + 127) >> NB_SHIFT;     // 391 buckets

  // Workspace: [s: N*4 f32 = 800000 B][avg: N*4 f32 = 800000 B]
  //            [gcur: NB_MAX u32 = 2 KB][grec: nb*CAP_B u32 ~ 8.0 MB]
  float*  s    = (float*)d_ws;
  float*  avg  = s + (size_t)N * 4;
  uint32* gcur = (uint32*)(avg + (size_t)N * 4);
  uint32* grec = gcur + NB_MAX;

  signal_kernel<<<(N + 3) / 4, 256, 0, stream>>>(x, core_w, core_b, s, gcur, N, nb);
  {
    int blocks = (E + P_CHUNK - 1) / P_CHUNK;   // 196
    part_kernel<<<blocks, 256, 0, stream>>>(src, tgt, gcur, grec, E, nb);
  }
  agg_kernel<<<nb, 256, 0, stream>>>(s, gcur, grec, avg, N);
  // MEASUREMENT: out_kernel twice (bit-identical stores; idempotent).
  // dur - 940.5 == cost(out_kernel). Removed next round.
  out_kernel<<<2048, 256, 0, stream>>>(x, avg, W_out, b_out, out, N);
  out_kernel<<<2048, 256, 0, stream>>>(x, avg, W_out, b_out, out, N);
}

// Round 9
// 957.452 us; speedup vs baseline: 1.1615x; 1.1615x over previous
//
#include <hip/hip_runtime.h>

// Problem constants (from reference): N=50000, F_IN=512, F_OUT=64, C=4, E=1.6M
#define F_IN 512
#define F_OUT 64
#define NB_SHIFT 7          // bucket = tgt >> 7  (128 nodes per bucket)
#define NB_MAX 512          // >= nb = 391
#define CAP_B 5120          // records/bucket; mean 4096, sigma 64 -> +16 sigma
#define P_CHUNK 8192        // edges per partition block (two-pass over L2)

typedef float v4f __attribute__((ext_vector_type(4)));
typedef unsigned int uint32;
typedef unsigned long long u64;

// ---------------------------------------------------------------------------
// ROUND 9 = MEASUREMENT ROUND #2. Identical to R7 except agg_kernel runs 3x
// (idempotent: pure function of gcur/grec/s -> avg). R8 measured
// O = out_kernel = 171.6 us (76% of write BW -> near floor). Ledger:
// P + Q ~ 220 us of the R7 total. This round: Q = (dur - 940.5)/2.
// Decision: Q<=40 -> attack P's scatter; Q in 40..100 -> merge+coalesce both;
// Q>=100 -> restructure aggregation.
// ---------------------------------------------------------------------------

// ---------------------------------------------------------------------------
// Phase 1: s[n][c] = tanh(dot(x[n], core_w[c]) + core_b[c]), one wave/node.
// Block 0 also zeroes the bucket reservation cursors.
// ---------------------------------------------------------------------------
__global__ __launch_bounds__(256) void signal_kernel(
    const float* __restrict__ x, const float* __restrict__ core_w,
    const float* __restrict__ core_b, float* __restrict__ s,
    uint32* __restrict__ gcur, int N, int nb) {
  if (blockIdx.x == 0) {
    for (int b = threadIdx.x; b < nb; b += 256) gcur[b] = 0;
  }

  int wave = (int)((blockIdx.x * blockDim.x + threadIdx.x) >> 6);
  int lane = threadIdx.x & 63;
  if (wave >= N) return;

  const v4f* xv = (const v4f*)(x + (size_t)wave * F_IN);
  v4f a0 = xv[lane * 2];
  v4f a1 = xv[lane * 2 + 1];

  float p[4];
#pragma unroll
  for (int c = 0; c < 4; ++c) {
    const v4f* wv = (const v4f*)(core_w + c * F_IN);
    v4f w0 = wv[lane * 2];
    v4f w1 = wv[lane * 2 + 1];
    p[c] = a0.x * w0.x + a0.y * w0.y + a0.z * w0.z + a0.w * w0.w +
           a1.x * w1.x + a1.y * w1.y + a1.z * w1.z + a1.w * w1.w;
  }
#pragma unroll
  for (int off = 32; off > 0; off >>= 1) {
#pragma unroll
    for (int c = 0; c < 4; ++c) p[c] += __shfl_down(p[c], off, 64);
  }
  if (lane == 0) {
    v4f r;
    r.x = tanhf(p[0] + core_b[0]);
    r.y = tanhf(p[1] + core_b[1]);
    r.z = tanhf(p[2] + core_b[2]);
    r.w = tanhf(p[3] + core_b[3]);
    ((v4f*)s)[wave] = r;
  }
}

// ---------------------------------------------------------------------------
// Phase P: partition P_CHUNK edges/block into bucket record arrays.
// Two passes over the (L2-resident) chunk: (A) LDS histogram, (reserve) one
// fabric atomic per non-empty bucket, (B) scatter with LDS cursor.
// Record u32 = (tgt & 127) | (src << 7)   [src < 50000 < 2^16 -> 23 bits].
// ---------------------------------------------------------------------------
__global__ __launch_bounds__(256) void part_kernel(
    const int* __restrict__ src, const int* __restrict__ tgt,
    uint32* __restrict__ gcur, uint32* __restrict__ grec, int E, int nb) {
  __shared__ uint32 hist[NB_MAX];
  __shared__ uint32 cur[NB_MAX];
  int tid = threadIdx.x;
  int start = (int)blockIdx.x * P_CHUNK;
  int end = start + P_CHUNK;
  if (end > E) end = E;

  for (int b = tid; b < nb; b += 256) hist[b] = 0;
  __syncthreads();

  // pass A: histogram (1 LDS atomic / edge)
  for (int i = start + tid; i < end; i += 256)
    atomicAdd(&hist[(uint32)tgt[i] >> NB_SHIFT], 1u);
  __syncthreads();

  // reserve: 1 returning fabric atomic per non-empty bucket
  for (int b = tid; b < nb; b += 256) {
    uint32 t = hist[b];
    cur[b] = t ? atomicAdd(&gcur[b], t) : 0u;
  }
  __syncthreads();

  // pass B: scatter (edge re-read hits this XCD's L2)
  for (int i = start + tid; i < end; i += 256) {
    uint32 v = (uint32)tgt[i];
    uint32 u = (uint32)src[i];
    uint32 b = v >> NB_SHIFT;
    uint32 pos = atomicAdd(&cur[b], 1u);       // LDS returning: cheap
    if (pos < CAP_B) grec[(size_t)b * CAP_B + pos] = (v & 127u) | (u << 7);
  }
}

// ---------------------------------------------------------------------------
// Phase Q: one block per bucket (391 blocks). Two u64 LDS accumulators per
// node (exact packed integer adds). Decode straight to avg[n] (4xf32).
// ---------------------------------------------------------------------------
__global__ __launch_bounds__(256) void agg_kernel(
    const float* __restrict__ s, const uint32* __restrict__ gcur,
    const uint32* __restrict__ grec, float* __restrict__ avg, int N) {
  int b = blockIdx.x;
  int tid = threadIdx.x;
  __shared__ u64 accA[128];
  __shared__ u64 accB[128];

  if (tid < 128) { accA[tid] = 0ull; accB[tid] = 0ull; }
  __syncthreads();

  uint32 cnt = gcur[b];
  if (cnt > CAP_B) cnt = CAP_B;
  const uint32* rp = grec + (size_t)b * CAP_B;
  for (uint32 r = tid; r < cnt; r += 256) {
    uint32 rec = rp[r];                 // coalesced
    uint32 node = rec & 127u;
    uint32 u = rec >> 7;
    v4f sv = ((const v4f*)s)[u];        // L2-resident gather (800 KB table)
    uint32 q0 = (uint32)__float2int_rn((sv.x + 1.0f) * 8388608.0f);  // 2^23
    uint32 q1 = (uint32)__float2int_rn((sv.y + 1.0f) * 8388608.0f);
    uint32 q2 = (uint32)__float2int_rn((sv.z + 1.0f) * 8388608.0f);
    uint32 q3 = (uint32)__float2int_rn((sv.w + 1.0f) * 131072.0f);   // 2^17
    atomicAdd(&accA[node], (u64)q0 | ((u64)q1 << 32));
    atomicAdd(&accB[node], (u64)q2 | ((u64)(q3 | (1u << 25)) << 32));
  }
  __syncthreads();

  int n = (b << NB_SHIFT) | tid;
  if (tid < 128 && n < N) {
    u64 wa = accA[tid];
    u64 wb = accB[tid];
    uint32 deg = (uint32)(wb >> 57);
    uint32 f3  = (uint32)(wb >> 32) & 0x1ffffffu;
    float fdeg = (float)deg;
    float inv = deg ? 1.0f / fdeg : 0.0f;
    v4f a;
    a.x = ((float)(uint32)wa         * 0x1p-23f - fdeg) * inv;
    a.y = ((float)(uint32)(wa >> 32) * 0x1p-23f - fdeg) * inv;
    a.z = ((float)(uint32)wb         * 0x1p-23f - fdeg) * inv;
    a.w = ((float)f3                 * 0x1p-17f - fdeg) * inv;
    ((v4f*)avg)[n] = a;                 // coalesced 16B
  }
}

// ---------------------------------------------------------------------------
// Phase 3: wave-per-node, grid-stride. avg[n] is plain 4xf32; 16 KB coalesced
// float4 stores per node. Measured R8: 171.6 us = 4.8 TB/s (near floor).
// ---------------------------------------------------------------------------
__global__ __launch_bounds__(256) void out_kernel(
    const float* __restrict__ x, const float* __restrict__ avg,
    const float* __restrict__ W_out, const float* __restrict__ b_out,
    float* __restrict__ out, int N) {
  int lane = threadIdx.x & 63;
  int gwave = (int)((blockIdx.x * blockDim.x + threadIdx.x) >> 6);
  int nwaves = (int)((gridDim.x * blockDim.x) >> 6);
  int col = lane & 15;          // this lane's output quad: o = col*4 .. col*4+3

  v4f w0 = ((const v4f*)W_out)[col * 4 + 0];
  v4f w1 = ((const v4f*)W_out)[col * 4 + 1];
  v4f w2 = ((const v4f*)W_out)[col * 4 + 2];
  v4f w3 = ((const v4f*)W_out)[col * 4 + 3];
  v4f bq = ((const v4f*)b_out)[col];

  for (int n = gwave; n < N; n += nwaves) {
    v4f a = ((const v4f*)avg)[n];       // uniform addr: broadcast load

    float t0 = a.x * w0.x + a.y * w0.y + a.z * w0.z + a.w * w0.w;
    float t1 = a.x * w1.x + a.y * w1.y + a.z * w1.z + a.w * w1.w;
    float t2 = a.x * w2.x + a.y * w2.y + a.z * w2.z + a.w * w2.w;
    float t3 = a.x * w3.x + a.y * w3.y + a.z * w3.z + a.w * w3.w;

    float xval = x[(size_t)n * F_IN + lane];  // lanes hold x[n][0..63]

    v4f* ov = (v4f*)(out + (size_t)n * (F_OUT * F_OUT));
#pragma unroll
    for (int it = 0; it < 16; ++it) {
      // slot = lane + it*64 ; f = slot>>4 = (lane>>4)+it*4 ; o4 = (lane&15)*4
      float xf = __shfl(xval, (lane >> 4) + it * 4, 64);
      v4f r;
      r.x = fmaxf(xf * t0 + bq.x, 0.0f);
      r.y = fmaxf(xf * t1 + bq.y, 0.0f);
      r.z = fmaxf(xf * t2 + bq.z, 0.0f);
      r.w = fmaxf(xf * t3 + bq.w, 0.0f);
      ov[lane + it * 64] = r;
    }
  }
}

extern "C" void kernel_launch(void* const* d_in, const int* in_sizes, int n_in,
                              void* d_out, int out_size, void* d_ws, size_t ws_size,
                              hipStream_t stream) {
  const float* x      = (const float*)d_in[0];
  const int*   eidx   = (const int*)d_in[1];
  const float* core_w = (const float*)d_in[2];
  const float* core_b = (const float*)d_in[3];
  const float* W_out  = (const float*)d_in[4];
  const float* b_out  = (const float*)d_in[5];
  float* out = (float*)d_out;

  const int N = in_sizes[0] / F_IN;         // 50000
  const int E = in_sizes[1] / 2;            // 1600000
  const int* src = eidx;
  const int* tgt = eidx + E;
  const int nb = (N + 127) >> NB_SHIFT;     // 391 buckets

  // Workspace: [s: N*4 f32 = 800000 B][avg: N*4 f32 = 800000 B]
  //            [gcur: NB_MAX u32 = 2 KB][grec: nb*CAP_B u32 ~ 8.0 MB]
  float*  s    = (float*)d_ws;
  float*  avg  = s + (size_t)N * 4;
  uint32* gcur = (uint32*)(avg + (size_t)N * 4);
  uint32* grec = gcur + NB_MAX;

  signal_kernel<<<(N + 3) / 4, 256, 0, stream>>>(x, core_w, core_b, s, gcur, N, nb);
  {
    int blocks = (E + P_CHUNK - 1) / P_CHUNK;   // 196
    part_kernel<<<blocks, 256, 0, stream>>>(src, tgt, gcur, grec, E, nb);
  }
  // MEASUREMENT: agg_kernel 3x (idempotent: pure function of gcur/grec/s).
  // Q = (dur - 940.5)/2. Extra runs removed next round.
  agg_kernel<<<nb, 256, 0, stream>>>(s, gcur, grec, avg, N);
  agg_kernel<<<nb, 256, 0, stream>>>(s, gcur, grec, avg, N);
  agg_kernel<<<nb, 256, 0, stream>>>(s, gcur, grec, avg, N);
  out_kernel<<<2048, 256, 0, stream>>>(x, avg, W_out, b_out, out, N);
}

// Round 10
// 931.970 us; speedup vs baseline: 1.1933x; 1.0273x over previous
//
#include <hip/hip_runtime.h>

// Problem constants (from reference): N=50000, F_IN=512, F_OUT=64, C=4, E=1.6M
#define F_IN 512
#define F_OUT 64
#define NB_SHIFT 7          // bucket = tgt >> 7  (128 nodes per bucket)
#define NB_MAX 512          // >= nb = 391
#define CAP_B 5120          // records/bucket; mean 4096, sigma 64 -> +16 sigma
#define P_CHUNK 8192        // edges per partition block

typedef float v4f __attribute__((ext_vector_type(4)));
typedef unsigned int uint32;
typedef unsigned long long u64;

// ---------------------------------------------------------------------------
// R9 ledger: ours ~420us = S(~25, model) + P(~190, BY ELIMINATION) + Q(8.5,
// measured) + O(171.6, measured). P's hog mechanism: pass-B issued 1.6M
// random 4B stores -> every 64B grec line written by ~12 blocks across all
// 8 non-coherent XCD L2s (false sharing + 1.6M store transactions).
// THIS ROUND: LDS counting-sort in part_kernel; records leave the block as
// coalesced per-bucket runs -> each grec line owned by exactly one block.
// ---------------------------------------------------------------------------

// ---------------------------------------------------------------------------
// Phase 1: s[n][c] = tanh(dot(x[n], core_w[c]) + core_b[c]), one wave/node.
// Block 0 also zeroes the bucket reservation cursors.
// ---------------------------------------------------------------------------
__global__ __launch_bounds__(256) void signal_kernel(
    const float* __restrict__ x, const float* __restrict__ core_w,
    const float* __restrict__ core_b, float* __restrict__ s,
    uint32* __restrict__ gcur, int N, int nb) {
  if (blockIdx.x == 0) {
    for (int b = threadIdx.x; b < nb; b += 256) gcur[b] = 0;
  }

  int wave = (int)((blockIdx.x * blockDim.x + threadIdx.x) >> 6);
  int lane = threadIdx.x & 63;
  if (wave >= N) return;

  const v4f* xv = (const v4f*)(x + (size_t)wave * F_IN);
  v4f a0 = xv[lane * 2];
  v4f a1 = xv[lane * 2 + 1];

  float p[4];
#pragma unroll
  for (int c = 0; c < 4; ++c) {
    const v4f* wv = (const v4f*)(core_w + c * F_IN);
    v4f w0 = wv[lane * 2];
    v4f w1 = wv[lane * 2 + 1];
    p[c] = a0.x * w0.x + a0.y * w0.y + a0.z * w0.z + a0.w * w0.w +
           a1.x * w1.x + a1.y * w1.y + a1.z * w1.z + a1.w * w1.w;
  }
#pragma unroll
  for (int off = 32; off > 0; off >>= 1) {
#pragma unroll
    for (int c = 0; c < 4; ++c) p[c] += __shfl_down(p[c], off, 64);
  }
  if (lane == 0) {
    v4f r;
    r.x = tanhf(p[0] + core_b[0]);
    r.y = tanhf(p[1] + core_b[1]);
    r.z = tanhf(p[2] + core_b[2]);
    r.w = tanhf(p[3] + core_b[3]);
    ((v4f*)s)[wave] = r;
  }
}

// ---------------------------------------------------------------------------
// Phase P v2: counting-sort partition.
//   A: LDS histogram of the chunk.
//   scan: Hillis-Steele inclusive scan (512 entries, 256 thr, 2/thread).
//   reserve: 1 returning fabric atomic per non-empty bucket; delta[b] maps
//            local slot -> global grec index.
//   B: re-read chunk (L2-warm), LDS-scatter into bucket-sorted order.
//   C: linear LDS sweep -> COALESCED run-writes; each grec 64B line is
//      written by exactly one block (no cross-XCD false sharing).
// Record u32 = (tgt & 127) | (src << 7)   [src < 50000 < 2^16 -> 23 bits].
// LDS: 32K sorted + 16K sbkt + 3x2K aux = 54 KB.
// ---------------------------------------------------------------------------
__global__ __launch_bounds__(256) void part_kernel(
    const int* __restrict__ src, const int* __restrict__ tgt,
    uint32* __restrict__ gcur, uint32* __restrict__ grec, int E, int nb) {
  __shared__ uint32 hist[NB_MAX];       // then reused as lcur (scatter cursor)
  __shared__ uint32 scan[NB_MAX];       // inclusive prefix
  __shared__ uint32 delta[NB_MAX];      // gdst = delta[b] + slot
  __shared__ uint32 sorted[P_CHUNK];
  __shared__ unsigned short sbkt[P_CHUNK];
  int tid = threadIdx.x;
  int start = (int)blockIdx.x * P_CHUNK;
  int end = start + P_CHUNK;
  if (end > E) end = E;

  for (int b = tid; b < NB_MAX; b += 256) hist[b] = 0;
  __syncthreads();

  // pass A: histogram
  for (int i = start + tid; i < end; i += 256)
    atomicAdd(&hist[(uint32)tgt[i] >> NB_SHIFT], 1u);
  __syncthreads();

  // inclusive scan of hist -> scan (512 entries, 2 per thread)
  scan[tid] = hist[tid];
  scan[tid + 256] = hist[tid + 256];
  __syncthreads();
  for (int off = 1; off < NB_MAX; off <<= 1) {
    uint32 v0 = (tid >= off) ? scan[tid - off] : 0u;
    uint32 v1 = scan[tid + 256 - off];   // tid+256 >= off always (off<=256)
    __syncthreads();
    scan[tid] += v0;
    scan[tid + 256] += v1;
    __syncthreads();
  }

  // reserve + delta; hist becomes the scatter cursor (init = exclusive start)
  for (int b = tid; b < nb; b += 256) {
    uint32 cntb = hist[b];
    uint32 ls = b ? scan[b - 1] : 0u;            // exclusive prefix
    uint32 gb = cntb ? atomicAdd(&gcur[b], cntb) : 0u;
    delta[b] = (uint32)b * CAP_B + gb - ls;
    hist[b] = ls;
  }
  __syncthreads();

  // pass B: LDS-scatter into bucket-sorted order (chunk re-read is L2-warm)
  for (int i = start + tid; i < end; i += 256) {
    uint32 v = (uint32)tgt[i];
    uint32 u = (uint32)src[i];
    uint32 b = v >> NB_SHIFT;
    uint32 lpos = atomicAdd(&hist[b], 1u);       // LDS cursor
    sorted[lpos] = (v & 127u) | (u << 7);
    sbkt[lpos] = (unsigned short)b;
  }
  __syncthreads();

  // pass C: coalesced run-writes
  int cnt = end - start;
  for (int i = tid; i < cnt; i += 256) {
    uint32 b = sbkt[i];
    uint32 gdst = delta[b] + (uint32)i;
    if (gdst < (b + 1u) * CAP_B) grec[gdst] = sorted[i];   // capacity guard
  }
}

// ---------------------------------------------------------------------------
// Phase Q: one block per bucket (391 blocks). Two u64 LDS accumulators per
// node (exact packed integer adds). Decode straight to avg[n] (4xf32).
// Measured R9: ~8.5 us warm.
// ---------------------------------------------------------------------------
__global__ __launch_bounds__(256) void agg_kernel(
    const float* __restrict__ s, const uint32* __restrict__ gcur,
    const uint32* __restrict__ grec, float* __restrict__ avg, int N) {
  int b = blockIdx.x;
  int tid = threadIdx.x;
  __shared__ u64 accA[128];
  __shared__ u64 accB[128];

  if (tid < 128) { accA[tid] = 0ull; accB[tid] = 0ull; }
  __syncthreads();

  uint32 cnt = gcur[b];
  if (cnt > CAP_B) cnt = CAP_B;
  const uint32* rp = grec + (size_t)b * CAP_B;
  for (uint32 r = tid; r < cnt; r += 256) {
    uint32 rec = rp[r];                 // coalesced
    uint32 node = rec & 127u;
    uint32 u = rec >> 7;
    v4f sv = ((const v4f*)s)[u];        // L2-resident gather (800 KB table)
    uint32 q0 = (uint32)__float2int_rn((sv.x + 1.0f) * 8388608.0f);  // 2^23
    uint32 q1 = (uint32)__float2int_rn((sv.y + 1.0f) * 8388608.0f);
    uint32 q2 = (uint32)__float2int_rn((sv.z + 1.0f) * 8388608.0f);
    uint32 q3 = (uint32)__float2int_rn((sv.w + 1.0f) * 131072.0f);   // 2^17
    atomicAdd(&accA[node], (u64)q0 | ((u64)q1 << 32));
    atomicAdd(&accB[node], (u64)q2 | ((u64)(q3 | (1u << 25)) << 32));
  }
  __syncthreads();

  int n = (b << NB_SHIFT) | tid;
  if (tid < 128 && n < N) {
    u64 wa = accA[tid];
    u64 wb = accB[tid];
    uint32 deg = (uint32)(wb >> 57);
    uint32 f3  = (uint32)(wb >> 32) & 0x1ffffffu;
    float fdeg = (float)deg;
    float inv = deg ? 1.0f / fdeg : 0.0f;
    v4f a;
    a.x = ((float)(uint32)wa         * 0x1p-23f - fdeg) * inv;
    a.y = ((float)(uint32)(wa >> 32) * 0x1p-23f - fdeg) * inv;
    a.z = ((float)(uint32)wb         * 0x1p-23f - fdeg) * inv;
    a.w = ((float)f3                 * 0x1p-17f - fdeg) * inv;
    ((v4f*)avg)[n] = a;                 // coalesced 16B
  }
}

// ---------------------------------------------------------------------------
// Phase 3: wave-per-node, grid-stride. Measured R8: 171.6 us = 4.8 TB/s
// (near write floor).
// ---------------------------------------------------------------------------
__global__ __launch_bounds__(256) void out_kernel(
    const float* __restrict__ x, const float* __restrict__ avg,
    const float* __restrict__ W_out, const float* __restrict__ b_out,
    float* __restrict__ out, int N) {
  int lane = threadIdx.x & 63;
  int gwave = (int)((blockIdx.x * blockDim.x + threadIdx.x) >> 6);
  int nwaves = (int)((gridDim.x * blockDim.x) >> 6);
  int col = lane & 15;          // this lane's output quad: o = col*4 .. col*4+3

  v4f w0 = ((const v4f*)W_out)[col * 4 + 0];
  v4f w1 = ((const v4f*)W_out)[col * 4 + 1];
  v4f w2 = ((const v4f*)W_out)[col * 4 + 2];
  v4f w3 = ((const v4f*)W_out)[col * 4 + 3];
  v4f bq = ((const v4f*)b_out)[col];

  for (int n = gwave; n < N; n += nwaves) {
    v4f a = ((const v4f*)avg)[n];       // uniform addr: broadcast load

    float t0 = a.x * w0.x + a.y * w0.y + a.z * w0.z + a.w * w0.w;
    float t1 = a.x * w1.x + a.y * w1.y + a.z * w1.z + a.w * w1.w;
    float t2 = a.x * w2.x + a.y * w2.y + a.z * w2.z + a.w * w2.w;
    float t3 = a.x * w3.x + a.y * w3.y + a.z * w3.z + a.w * w3.w;

    float xval = x[(size_t)n * F_IN + lane];  // lanes hold x[n][0..63]

    v4f* ov = (v4f*)(out + (size_t)n * (F_OUT * F_OUT));
#pragma unroll
    for (int it = 0; it < 16; ++it) {
      // slot = lane + it*64 ; f = slot>>4 = (lane>>4)+it*4 ; o4 = (lane&15)*4
      float xf = __shfl(xval, (lane >> 4) + it * 4, 64);
      v4f r;
      r.x = fmaxf(xf * t0 + bq.x, 0.0f);
      r.y = fmaxf(xf * t1 + bq.y, 0.0f);
      r.z = fmaxf(xf * t2 + bq.z, 0.0f);
      r.w = fmaxf(xf * t3 + bq.w, 0.0f);
      ov[lane + it * 64] = r;
    }
  }
}

extern "C" void kernel_launch(void* const* d_in, const int* in_sizes, int n_in,
                              void* d_out, int out_size, void* d_ws, size_t ws_size,
                              hipStream_t stream) {
  const float* x      = (const float*)d_in[0];
  const int*   eidx   = (const int*)d_in[1];
  const float* core_w = (const float*)d_in[2];
  const float* core_b = (const float*)d_in[3];
  const float* W_out  = (const float*)d_in[4];
  const float* b_out  = (const float*)d_in[5];
  float* out = (float*)d_out;

  const int N = in_sizes[0] / F_IN;         // 50000
  const int E = in_sizes[1] / 2;            // 1600000
  const int* src = eidx;
  const int* tgt = eidx + E;
  const int nb = (N + 127) >> NB_SHIFT;     // 391 buckets

  // Workspace: [s: N*4 f32 = 800000 B][avg: N*4 f32 = 800000 B]
  //            [gcur: NB_MAX u32 = 2 KB][grec: nb*CAP_B u32 ~ 8.0 MB]
  float*  s    = (float*)d_ws;
  float*  avg  = s + (size_t)N * 4;
  uint32* gcur = (uint32*)(avg + (size_t)N * 4);
  uint32* grec = gcur + NB_MAX;

  signal_kernel<<<(N + 3) / 4, 256, 0, stream>>>(x, core_w, core_b, s, gcur, N, nb);
  {
    int blocks = (E + P_CHUNK - 1) / P_CHUNK;   // 196
    part_kernel<<<blocks, 256, 0, stream>>>(src, tgt, gcur, grec, E, nb);
  }
  agg_kernel<<<nb, 256, 0, stream>>>(s, gcur, grec, avg, N);
  out_kernel<<<2048, 256, 0, stream>>>(x, avg, W_out, b_out, out, N);
}